// Round 8
// baseline (14.208 us; speedup 1.0000x reference)
//
#include <hip/hip_runtime.h>

// P=40000, DEG=16, CI=CO=16.
// Single kernel, no workspace. Contraction order:
//   h[p][d][i] = sum_n r[p,n,d] * feat[nbr(p,n)][i]     (edge loop: feat only, L2-resident)
//   out[p][o]  = sum_d sum_i W[d][o][i] * h[p][d][i]
// Block = 256 = 16 points x 16 lanes (li = i). DS-pipe-minimized:
//   - radii: 12x same-address dwordx4 GLOBAL loads per lane (L1 broadcast, no LDS)
//   - W: transposed LDS s_Wt[i][d*16+o] (pad 52 -> 2-way bank aliasing = free),
//        each lane reads its COLUMN W[d][o][li] as 12x b128
//   - h: never goes to LDS; po[16] partials per lane, then 15-shuffle
//        recursive-halving exchange (xor 8,4,2,1 within 16 lanes) lands out[p][li].

__global__ __launch_bounds__(256) void k_conv(const float* __restrict__ feat,
                                              const float* __restrict__ radii,
                                              const float* __restrict__ W,
                                              const int* __restrict__ bs,
                                              float* __restrict__ out,
                                              int P) {
    __shared__ __align__(16) float s_Wt[16][52];  // [i][d*16+o], pad 48->52
    __shared__ __align__(16) int   s_nbr[16][16]; // [lp][n]

    const int tid = threadIdx.x;
    const int pbase = blockIdx.x * 16;
    const int lp = tid >> 4;          // local point 0..15
    const int li = tid & 15;          // input channel i / final output channel o

    // stage W transposed: s_Wt[i][d*16+o] = W[d][o][i]
    for (int t = tid; t < 768; t += 256) {
        const int d = t >> 8, o = (t >> 4) & 15, i = t & 15;
        s_Wt[i][d * 16 + o] = W[t];
    }
    // stage neighbor indices
    {
        const int p = pbase + lp;
        s_nbr[lp][li] = (p < P) ? bs[(size_t)p * 17 + 1 + li] : 0;
    }
    __syncthreads();

    const int p = pbase + lp;
    if (p >= P) return;               // uniform per 16-lane group; shuffles stay in-group

    // radii row: 12 same-address float4 global loads (16B-aligned: p*192 bytes)
    float rr[48];
    {
        const float4* r4 = reinterpret_cast<const float4*>(radii + (size_t)p * 48);
#pragma unroll
        for (int j = 0; j < 12; ++j) {
            const float4 v = r4[j];
            rr[j*4+0] = v.x; rr[j*4+1] = v.y; rr[j*4+2] = v.z; rr[j*4+3] = v.w;
        }
    }
    // neighbor row: 4x b128 broadcast from LDS
    int nb[16];
    {
        const int4* nb4 = reinterpret_cast<const int4*>(&s_nbr[lp][0]);
#pragma unroll
        for (int j = 0; j < 4; ++j) {
            const int4 v = nb4[j];
            nb[j*4+0] = v.x; nb[j*4+1] = v.y; nb[j*4+2] = v.z; nb[j*4+3] = v.w;
        }
    }

    // Phase A: h[d] for i = li
    float h0 = 0.f, h1 = 0.f, h2 = 0.f;
#pragma unroll
    for (int n = 0; n < 16; ++n) {
        const float fv = feat[((size_t)nb[n] << 4) + li];  // 64B coalesced per group
        h0 += rr[n*3+0] * fv;
        h1 += rr[n*3+1] * fv;
        h2 += rr[n*3+2] * fv;
    }

    // Phase B: po[o] = sum_d W[d][o][li] * h[d]  (W column via s_Wt row li)
    float po[16];
    {
        const float4* w4 = reinterpret_cast<const float4*>(&s_Wt[li][0]);  // row li: 208B-aligned
#pragma unroll
        for (int j = 0; j < 4; ++j) {                 // d=0
            const float4 w = w4[j];
            po[j*4+0] = w.x*h0; po[j*4+1] = w.y*h0; po[j*4+2] = w.z*h0; po[j*4+3] = w.w*h0;
        }
#pragma unroll
        for (int j = 0; j < 4; ++j) {                 // d=1
            const float4 w = w4[4+j];
            po[j*4+0] += w.x*h1; po[j*4+1] += w.y*h1; po[j*4+2] += w.z*h1; po[j*4+3] += w.w*h1;
        }
#pragma unroll
        for (int j = 0; j < 4; ++j) {                 // d=2
            const float4 w = w4[8+j];
            po[j*4+0] += w.x*h2; po[j*4+1] += w.y*h2; po[j*4+2] += w.z*h2; po[j*4+3] += w.w*h2;
        }
    }

    // Recursive-halving transpose-reduce within the 16-lane group:
    // after stages xor 8,4,2,1, lane li holds out[p][o=li].
    const bool b8 = (li & 8) != 0;
    float v8[8];
#pragma unroll
    for (int k = 0; k < 8; ++k) {
        const float send = b8 ? po[k] : po[k+8];
        const float keep = b8 ? po[k+8] : po[k];
        v8[k] = keep + __shfl_xor(send, 8, 16);
    }
    const bool b4 = (li & 4) != 0;
    float v4[4];
#pragma unroll
    for (int k = 0; k < 4; ++k) {
        const float send = b4 ? v8[k] : v8[k+4];
        const float keep = b4 ? v8[k+4] : v8[k];
        v4[k] = keep + __shfl_xor(send, 4, 16);
    }
    const bool b2 = (li & 2) != 0;
    float v2[2];
#pragma unroll
    for (int k = 0; k < 2; ++k) {
        const float send = b2 ? v4[k] : v4[k+2];
        const float keep = b2 ? v4[k+2] : v4[k];
        v2[k] = keep + __shfl_xor(send, 2, 16);
    }
    const bool b1 = (li & 1) != 0;
    {
        const float send = b1 ? v2[0] : v2[1];
        const float keep = b1 ? v2[1] : v2[0];
        const float res = keep + __shfl_xor(send, 1, 16);
        out[(size_t)p * 16 + li] = res;
    }
}

extern "C" void kernel_launch(void* const* d_in, const int* in_sizes, int n_in,
                              void* d_out, int out_size, void* d_ws, size_t ws_size,
                              hipStream_t stream) {
    const float* feat  = (const float*)d_in[0];   // [P,16] f32
    const float* radii = (const float*)d_in[1];   // [E,3]  f32
    const float* W     = (const float*)d_in[2];   // [3,16,16] f32
    const int*   bs    = (const int*)d_in[3];     // [P,17] i32
    float* out = (float*)d_out;                   // [P,16] f32

    const int P = in_sizes[0] / 16;
    const int grid = (P + 15) / 16;
    k_conv<<<grid, 256, 0, stream>>>(feat, radii, W, bs, out, P);
}